// Round 4
// baseline (639.255 us; speedup 1.0000x reference)
//
#include <hip/hip_runtime.h>
#include <hip/hip_fp16.h>

// Euler neural-ODE scan: B=1024, L=512, S=64, U=32, H=512, dt=0.1.
// 64 blocks x 512 threads (8 waves); block owns 16 batch rows for all steps.
// Round-4 structure:
//  * u off the critical path: uacc = b1 + u(t+1)_hi@W1u + u(t+1)_lo@W1u is
//    computed DURING step t (8 MFMAs, reg-fed from per-wave global loads of u,
//    L2-resident). z in LDS holds only state (hi/lo), K=128: 4 ds_reads,
//    16 dependent MFMAs in GEMM1 (acc1 starts from uacc).
//  * pi-permutation (round 3): GEMM1 C-frags pack directly into GEMM2 B-frags;
//    wave w computes GEMM2 K-slice [64w,64w+64) from its own registers.
//  * 8-way P2: every wave owns 8 s-cols (f32x2 per lane): 8x ds_read_b64
//    partial reduce (2-way banks = free), fp32 state, f32x2 out store,
//    state hi/lo f16x2 z-writes.
//  * lgkmcnt-only barriers (raw s_barrier): out-stores and u prefetch loads
//    are never drained at barriers (no vmcnt(0) on the critical path).

typedef _Float16 f16;
typedef __attribute__((ext_vector_type(2))) _Float16 f16x2;
typedef __attribute__((ext_vector_type(8))) _Float16 f16x8;
typedef __attribute__((ext_vector_type(2))) float f32x2;
typedef __attribute__((ext_vector_type(4))) float f32x4;

#define MFMA16(a, b, c) __builtin_amdgcn_mfma_f32_16x16x32_f16((a), (b), (c), 0, 0, 0)

// LDS-only barrier: drain LDS ops (writes visible + in-flight reads landed),
// then raw s_barrier. Global (vmcnt) traffic intentionally NOT drained.
#define BAR() do { asm volatile("s_waitcnt lgkmcnt(0)" ::: "memory"); \
                   __builtin_amdgcn_s_barrier();                      \
                   asm volatile("" ::: "memory"); } while (0)

__device__ __forceinline__ float tanh_fast(float x) {
    float t = __builtin_amdgcn_exp2f(x * 2.885390081777927f);  // e^{2x}
    float r = __builtin_amdgcn_rcpf(t + 1.0f);
    return __builtin_fmaf(-2.0f, r, 1.0f);
}

__global__ __launch_bounds__(512, 2)
void euler_kernel(const float* __restrict__ init,
                  const float* __restrict__ uin,
                  const float* __restrict__ W1,
                  const float* __restrict__ b1,
                  const float* __restrict__ W2,
                  const float* __restrict__ b2,
                  float* __restrict__ out) {
    const int L = 512, S = 64, U = 32, H = 512;
    const int tid  = threadIdx.x;
    const int lane = tid & 63;
    const int w    = tid >> 6;      // wave 0..7
    const int g    = lane >> 4;     // k-group 0..3
    const int r16  = lane & 15;
    const int b0   = blockIdx.x * 16;

    // z (state only): 4 kk-tiles x 64 chunks x 8 f16 (hi: 0..127, lo: 128..255)
    __shared__ f16   zbuf[256 * 8];          // 4 KB
    // GEMM2 partials: chunk(ww, nf2, lane), f32x4 each
    __shared__ float pbuf[8 * 256 * 4];      // 32 KB

    // ---- W1^T A-fragments, pi-permuted H-columns ----
    f16x8 W1F[4][4];   // state rows (kk 0,1 = hi; 2,3 = lo share W1 rows 0..63)
    f16x8 W1Fu[2][4];  // u rows (hi/lo share W1 rows 64..95)
    #pragma unroll
    for (int kk = 0; kk < 6; ++kk)
      #pragma unroll
      for (int nf = 0; nf < 4; ++nf) {
          const int hcol = w * 64 + 32 * (nf >> 1) + 8 * (r16 >> 2) + 4 * (nf & 1) + (r16 & 3);
          #pragma unroll
          for (int j = 0; j < 8; ++j) {
              int k  = kk * 32 + g * 8 + j;
              int kr = (k < 128) ? (k & 63) : (64 + (k & 31));
              f16 v  = (f16)W1[kr * H + hcol];
              if (kk < 4) W1F[kk][nf][j] = v; else W1Fu[kk - 4][nf][j] = v;
          }
      }
    f32x4 b1v[4];
    #pragma unroll
    for (int nf = 0; nf < 4; ++nf)
        b1v[nf] = *(const f32x4*)&b1[w * 64 + 32 * (nf >> 1) + 4 * (nf & 1) + 8 * g];

    // ---- W2^T A-fragments, wave's K-slice [w*64, w*64+64) ----
    f16x8 W2F[2][4];
    #pragma unroll
    for (int a = 0; a < 2; ++a)
      #pragma unroll
      for (int nf2 = 0; nf2 < 4; ++nf2)
        #pragma unroll
        for (int j = 0; j < 8; ++j) {
            int k = w * 64 + a * 32 + g * 8 + j;
            W2F[a][nf2][j] = (f16)W2[k * S + nf2 * 16 + r16];
        }

    // ---- state slice: wave w owns s in [8w, 8w+8); lane: s0 = 8w+2g, batch r16
    f32x2 b2v    = *(const f32x2*)&b2[w * 8 + g * 2];
    f32x2 stateF = *(const f32x2*)&init[(size_t)(b0 + r16) * S + w * 8 + g * 2];
    // z chunk for this lane's state pair: kk = w>>2, gz = w&3, f16 slot 2g
    const int zci = ((w >> 2) * 64 + (w & 3) * 16 + r16) * 8 + g * 2;
    {
        f16 h0 = (f16)stateF[0], h1 = (f16)stateF[1];
        f16x2 hi2, lo2;
        hi2[0] = h0;                              hi2[1] = h1;
        lo2[0] = (f16)(stateF[0] - (float)h0);    lo2[1] = (f16)(stateF[1] - (float)h1);
        *(f16x2*)&zbuf[zci]        = hi2;
        *(f16x2*)&zbuf[zci + 1024] = lo2;
    }

    // ---- u prologue: uacc = b1 + u(0)@W1u ; then ua <- u(1) ----
    const float* uptr = uin + (size_t)(b0 + r16) * L * U + g * 8;
    f32x4 ua0 = *(const f32x4*)uptr;
    f32x4 ua1 = *(const f32x4*)(uptr + 4);
    f32x4 uacc[4];
    #pragma unroll
    for (int nf = 0; nf < 4; ++nf) uacc[nf] = b1v[nf];
    {
        f16x8 uh, ul;
        #pragma unroll
        for (int j = 0; j < 4; ++j) {
            f16 h0 = (f16)ua0[j]; uh[j] = h0;     ul[j] = (f16)(ua0[j] - (float)h0);
            f16 h1 = (f16)ua1[j]; uh[4 + j] = h1; ul[4 + j] = (f16)(ua1[j] - (float)h1);
        }
        #pragma unroll
        for (int nf = 0; nf < 4; ++nf) uacc[nf] = MFMA16(W1Fu[0][nf], uh, uacc[nf]);
        #pragma unroll
        for (int nf = 0; nf < 4; ++nf) uacc[nf] = MFMA16(W1Fu[1][nf], ul, uacc[nf]);
    }
    ua0 = *(const f32x4*)(uptr + U);
    ua1 = *(const f32x4*)(uptr + U + 4);
    BAR();

    // P2 partial-read base: nf2 = w>>1, gs = 2*(w&1) + (g>>1), sub = 2*(g&1)
    const int pbase = ((w >> 1) * 64 + (2 * (w & 1) + (g >> 1)) * 16 + r16) * 4 + 2 * (g & 1);

    #pragma unroll 1
    for (int t = 0; t < L; ++t) {
        // ---- P1: state z-read, GEMM1 (init from uacc), tanh+pack, GEMM2 ----
        f16x8 zf[4];
        #pragma unroll
        for (int kk = 0; kk < 4; ++kk)
            zf[kk] = *(const f16x8*)&zbuf[(kk * 64 + lane) * 8];
        f32x4 acc1[4];
        #pragma unroll
        for (int nf = 0; nf < 4; ++nf) acc1[nf] = uacc[nf];
        #pragma unroll
        for (int kk = 0; kk < 4; ++kk)
          #pragma unroll
          for (int nf = 0; nf < 4; ++nf)
            acc1[nf] = MFMA16(W1F[kk][nf], zf[kk], acc1[nf]);
        f16x8 hb[2];
        #pragma unroll
        for (int a = 0; a < 2; ++a)
          #pragma unroll
          for (int j8 = 0; j8 < 8; ++j8)
            hb[a][j8] = (f16)tanh_fast(acc1[a * 2 + (j8 >> 2)][j8 & 3]);
        f32x4 acc2[4];
        #pragma unroll
        for (int nf2 = 0; nf2 < 4; ++nf2) acc2[nf2] = (f32x4){0.f, 0.f, 0.f, 0.f};
        #pragma unroll
        for (int a = 0; a < 2; ++a)
          #pragma unroll
          for (int nf2 = 0; nf2 < 4; ++nf2)
            acc2[nf2] = MFMA16(W2F[a][nf2], hb[a], acc2[nf2]);
        #pragma unroll
        for (int nf2 = 0; nf2 < 4; ++nf2)
            *(f32x4*)&pbuf[(w * 256 + nf2 * 64 + lane) * 4] = acc2[nf2];

        // ---- off-path: uacc(t+1) = b1 + u(t+1)@W1u ; prefetch u(t+2) ----
        #pragma unroll
        for (int nf = 0; nf < 4; ++nf) uacc[nf] = b1v[nf];
        {
            f16x8 uh, ul;
            #pragma unroll
            for (int j = 0; j < 4; ++j) {
                f16 h0 = (f16)ua0[j]; uh[j] = h0;     ul[j] = (f16)(ua0[j] - (float)h0);
                f16 h1 = (f16)ua1[j]; uh[4 + j] = h1; ul[4 + j] = (f16)(ua1[j] - (float)h1);
            }
            #pragma unroll
            for (int nf = 0; nf < 4; ++nf) uacc[nf] = MFMA16(W1Fu[0][nf], uh, uacc[nf]);
            #pragma unroll
            for (int nf = 0; nf < 4; ++nf) uacc[nf] = MFMA16(W1Fu[1][nf], ul, uacc[nf]);
        }
        {
            int tp = (t + 2 < L) ? (t + 2) : (L - 1);
            const float* up = uptr + (size_t)tp * U;
            ua0 = *(const f32x4*)up;
            ua1 = *(const f32x4*)(up + 4);
        }
        BAR();

        // ---- P2: 8-way partial reduce, state update, store, z-write ----
        f32x2 sum = (f32x2){0.f, 0.f};
        #pragma unroll
        for (int ww = 0; ww < 8; ++ww) {
            f32x2 p = *(const f32x2*)&pbuf[ww * 1024 + pbase];
            sum[0] += p[0];
            sum[1] += p[1];
        }
        float s0 = __builtin_fmaf(0.1f, sum[0] + b2v[0], stateF[0]);
        float s1 = __builtin_fmaf(0.1f, sum[1] + b2v[1], stateF[1]);
        stateF[0] = s0; stateF[1] = s1;
        *(f32x2*)&out[((size_t)(b0 + r16) * L + t) * S + w * 8 + g * 2] = stateF;
        f16 h0 = (f16)s0, h1 = (f16)s1;
        f16x2 hi2, lo2;
        hi2[0] = h0;                     hi2[1] = h1;
        lo2[0] = (f16)(s0 - (float)h0);  lo2[1] = (f16)(s1 - (float)h1);
        *(f16x2*)&zbuf[zci]        = hi2;
        *(f16x2*)&zbuf[zci + 1024] = lo2;
        BAR();
    }
}

extern "C" void kernel_launch(void* const* d_in, const int* in_sizes, int n_in,
                              void* d_out, int out_size, void* d_ws, size_t ws_size,
                              hipStream_t stream) {
    const float* init = (const float*)d_in[0];
    const float* uin  = (const float*)d_in[1];
    const float* W1   = (const float*)d_in[2];
    const float* b1   = (const float*)d_in[3];
    const float* W2   = (const float*)d_in[4];
    const float* b2   = (const float*)d_in[5];
    euler_kernel<<<dim3(64), dim3(512), 0, stream>>>(init, uin, W1, b1, W2, b2,
                                                     (float*)d_out);
}